// Round 3
// baseline (61.144 us; speedup 1.0000x reference)
//
#include <hip/hip_runtime.h>

#define AA (-0.75f)

__device__ __forceinline__ float k1f(float x) {
    return ((AA + 2.0f) * x - (AA + 3.0f)) * x * x + 1.0f;
}
__device__ __forceinline__ float k2f(float x) {
    return ((AA * x - 5.0f * AA) * x + 8.0f * AA) * x - 4.0f * AA;
}

__device__ __forceinline__ int reflect_clip(int idx, int size) {
    int span = size - 1;
    int i = idx < 0 ? -idx : idx;
    i = i % (2 * span);
    if (i > span) i = 2 * span - i;
    return i;
}

// LDS bank swizzle: logical element a -> a ^ ((a>>5)&31). Bijective within a
// 512-float row; maps stride-4 and stride-8 lane patterns (r=0.5/0.25 gathers)
// to <=2-way bank aliasing (free on CDNA).
__device__ __forceinline__ int swz(int a) { return a ^ ((a >> 5) & 31); }

// Separable bicubic. One block per (b,h), 256 threads.
// Phase 1: vertical 4-tap (coalesced float4 global loads) -> swizzled LDS row.
// Phase 2: horizontal 4-tap gather from LDS, 2 consecutive cols/thread,
//          float2 stores, tap indices reused across all 8 channels.
__global__ __launch_bounds__(256)
void pds3_kernel(const float* __restrict__ x,
                 const float* __restrict__ rate,
                 const float* __restrict__ center,
                 float* __restrict__ out)
{
    constexpr int C = 8, H = 512, W = 512;

    // XCD-chunked remap (8192 % 8 == 0 -> bijective): h-neighbors share input
    // rows -> same-XCD L2 locality.
    const int orig = blockIdx.x;
    const int id = (orig & 7) * 1024 + (orig >> 3);
    const int b = id >> 9;
    const int h = id & (H - 1);

    const float r  = rate[b];
    const float cx = center[2 * b + 0];
    const float cy = center[2 * b + 1];

    // ---- y taps (block-uniform) ----
    const float gy = 0.00390625f * (float)h - 1.0f;
    const float Gy = (gy - cy) / r + cy;
    const float iy = (Gy + 1.0f) * 0.5f * 511.0f;
    const float y0 = floorf(iy);
    const float ty = iy - y0;
    const int   y0i = (int)y0;
    const float wy0 = k2f(ty + 1.0f);
    const float wy1 = k1f(ty);
    const float wy2 = k1f(1.0f - ty);
    const float wy3 = k2f(2.0f - ty);
    const size_t ro0 = (size_t)reflect_clip(y0i - 1, H) * W;
    const size_t ro1 = (size_t)reflect_clip(y0i    , H) * W;
    const size_t ro2 = (size_t)reflect_clip(y0i + 1, H) * W;
    const size_t ro3 = (size_t)reflect_clip(y0i + 2, H) * W;

    // ---- per-thread x taps for columns w0 = 2t, w1 = 2t+1 ----
    const int t = threadIdx.x;
    int   sA0, sA1, sA2, sA3, sB0, sB1, sB2, sB3;   // swizzled LDS indices
    float wxA0, wxA1, wxA2, wxA3, wxB0, wxB1, wxB2, wxB3;
    {
        const int w = 2 * t;
        const float gx = 0.00390625f * (float)w - 1.0f;
        const float Gx = (gx - cx) / r + cx;
        const float ix = (Gx + 1.0f) * 0.5f * 511.0f;
        const float x0 = floorf(ix);
        const float tx = ix - x0;
        const int x0i = (int)x0;
        wxA0 = k2f(tx + 1.0f); wxA1 = k1f(tx);
        wxA2 = k1f(1.0f - tx); wxA3 = k2f(2.0f - tx);
        sA0 = swz(reflect_clip(x0i - 1, W)); sA1 = swz(reflect_clip(x0i,     W));
        sA2 = swz(reflect_clip(x0i + 1, W)); sA3 = swz(reflect_clip(x0i + 2, W));
    }
    {
        const int w = 2 * t + 1;
        const float gx = 0.00390625f * (float)w - 1.0f;
        const float Gx = (gx - cx) / r + cx;
        const float ix = (Gx + 1.0f) * 0.5f * 511.0f;
        const float x0 = floorf(ix);
        const float tx = ix - x0;
        const int x0i = (int)x0;
        wxB0 = k2f(tx + 1.0f); wxB1 = k1f(tx);
        wxB2 = k1f(1.0f - tx); wxB3 = k2f(2.0f - tx);
        sB0 = swz(reflect_clip(x0i - 1, W)); sB1 = swz(reflect_clip(x0i,     W));
        sB2 = swz(reflect_clip(x0i + 1, W)); sB3 = swz(reflect_clip(x0i + 2, W));
    }

    __shared__ float tmp[C][W];   // 16 KiB, swizzled rows

    // ---- vertical pass ----
    const float* imgb = x + (size_t)b * C * H * W;
    #pragma unroll
    for (int k = 0; k < 4; ++k) {
        const int g  = t + k * 256;          // 1024 groups = 8 c x 128
        const int c  = g >> 7;
        const int c4 = (g & 127) << 2;       // logical float index, 16B aligned
        const float* img = imgb + (size_t)c * (H * W);
        const float4 a0 = *(const float4*)(img + ro0 + c4);
        const float4 a1 = *(const float4*)(img + ro1 + c4);
        const float4 a2 = *(const float4*)(img + ro2 + c4);
        const float4 a3 = *(const float4*)(img + ro3 + c4);
        float e0 = wy0 * a0.x + wy1 * a1.x + wy2 * a2.x + wy3 * a3.x;
        float e1 = wy0 * a0.y + wy1 * a1.y + wy2 * a2.y + wy3 * a3.y;
        float e2 = wy0 * a0.z + wy1 * a1.z + wy2 * a2.z + wy3 * a3.z;
        float e3 = wy0 * a0.w + wy1 * a1.w + wy2 * a2.w + wy3 * a3.w;
        // swizzled float4 write: group lands at base = c4 ^ (v&~3),
        // components permuted by p = v&3 (slot s holds source s^p).
        const int v    = (c4 >> 5) & 31;
        const int base = c4 ^ (v & ~3);
        const int p    = v & 3;
        const bool q1 = (p & 1) != 0;
        const bool q2 = (p & 2) != 0;
        float t0 = q1 ? e1 : e0;
        float t1 = q1 ? e0 : e1;
        float t2 = q1 ? e3 : e2;
        float t3 = q1 ? e2 : e3;
        float u0 = q2 ? t2 : t0;
        float u1 = q2 ? t3 : t1;
        float u2 = q2 ? t0 : t2;
        float u3 = q2 ? t1 : t3;
        *(float4*)&tmp[c][base] = make_float4(u0, u1, u2, u3);
    }
    __syncthreads();

    // ---- horizontal pass ----
    float* obase = out + ((size_t)b * C * H + h) * W + 2 * t;
    #pragma unroll
    for (int c = 0; c < C; ++c) {
        const float* tr = tmp[c];
        const float s0 = wxA0 * tr[sA0] + wxA1 * tr[sA1]
                       + wxA2 * tr[sA2] + wxA3 * tr[sA3];
        const float s1 = wxB0 * tr[sB0] + wxB1 * tr[sB1]
                       + wxB2 * tr[sB2] + wxB3 * tr[sB3];
        *(float2*)(obase + (size_t)c * (H * W)) = make_float2(s0, s1);
    }
}

extern "C" void kernel_launch(void* const* d_in, const int* in_sizes, int n_in,
                              void* d_out, int out_size, void* d_ws, size_t ws_size,
                              hipStream_t stream) {
    const float* x      = (const float*)d_in[0];
    const float* rate   = (const float*)d_in[1];
    const float* center = (const float*)d_in[2];
    float* out          = (float*)d_out;

    constexpr int B = 16, H = 512;
    dim3 grid(B * H);
    dim3 block(256);
    pds3_kernel<<<grid, block, 0, stream>>>(x, rate, center, out);
}